// Round 6
// baseline (2096.800 us; speedup 1.0000x reference)
//
#include <hip/hip_runtime.h>
#include <hip/hip_fp16.h>

// Persistent fused GRU + value head, MI355X (gfx950).
// T=512,B=256,I=64,H=512. 256 blocks = 16 batch groups x 16 hidden slices (STATIC
// mapping — R5's runtime-XCD grouping was not replay-safe: XCD-local L2 sync state
// survives graph replays as dirty lines that memset/poison at the MALL never
// invalidate. ALL cross-block state here lives at the MALL via sc0sc1/agent ops.)
//
// Per block: 2 MFMA waves (weights stationary as A-operands; gates in registers;
// one 8B h-store/lane) + 1 SERVICE wave that polls 32 per-wave flag words (one
// ballot round trip, zero RMWs) and prefetches h_t into an LDS ping-pong during
// the MFMA waves' tail — observe+load latency overlaps peers' gate/store/drain.

#define T_  512
#define B_  256
#define I_  64
#define H_  512
#define NBG 16
#define NHS 16
#define BT  16                  // batch rows per group
#define HS  32                  // hidden units per block
#define BLOCK 192
#define NSL 32                  // value-head slices (j,wv)
#define HROW 520                // padded LDS row (halves): 1040 B, 16B-aligned,
                                // stride%32dw==4 -> uniform 8 lanes/bank-window on b128
#define FLAG_STRIDE 16          // dwords: 64 B between flag words

typedef _Float16 f16;
typedef _Float16 f16x8 __attribute__((ext_vector_type(8)));
typedef float    f32x4 __attribute__((ext_vector_type(4)));
typedef unsigned int u32x2 __attribute__((ext_vector_type(2)));

__device__ __forceinline__ float sigmoid_f(float x) { return 1.f / (1.f + __expf(-x)); }
__device__ __forceinline__ float tanh_f(float x) {
    float e2 = __expf(2.f * x);
    return 1.f - 2.f / (e2 + 1.f);
}

__global__ __launch_bounds__(BLOCK, 1) void gru_persistent(
    const float* __restrict__ X, const float* __restrict__ Wih,
    const float* __restrict__ Whh, const float* __restrict__ bih,
    const float* __restrict__ bhh, const float* __restrict__ vw,
    const float* __restrict__ bias, float* __restrict__ Vout,
    f16* __restrict__ hbuf, unsigned int* __restrict__ flags,
    float* __restrict__ part, const int use_part)
{
    const int blk  = blockIdx.x;
    const int g    = (blk & 7) * 2 + (blk >> 7);   // group members share blk%8 (XCD heuristic)
    const int j    = (blk >> 3) & 15;
    const int b0   = g * BT;
    const int tid  = threadIdx.x;
    const int wv   = tid >> 6;
    const int lane = tid & 63;
    const int quad = lane >> 4;
    const int mrow = lane & 15;

    __shared__ __align__(16) f16 sh_h[2][BT][HROW];   // h ping-pong, written by service
    unsigned int* gflags = flags + (size_t)g * (32 * FLAG_STRIDE);

    // zero slot 0 (h_{-1} = 0); slot 1 is filled by service before first use
    for (int e = tid; e < BT * HROW; e += BLOCK) ((f16*)sh_h)[e] = (f16)0.f;

    if (wv < 2) {
        // ============== MFMA waves: weights=A (units on M), h/x=B (batch on N) ==============
        // A[m=lane&15 -> unit][k=quad*8+e]; D: row=quad*4+r -> unit, col=lane&15 -> batch
        f16x8 wh[3][16];
        f16x8 wxA[3][2];
        const int um = HS * j + wv * 16 + mrow;
        #pragma unroll
        for (int g3 = 0; g3 < 3; g3++) {
            const size_t grow = (size_t)(g3 * H_ + um);
            #pragma unroll
            for (int kt = 0; kt < 16; kt++) {
                const float* src = Whh + grow * H_ + kt * 32 + quad * 8;
                #pragma unroll
                for (int e = 0; e < 8; e++) wh[g3][kt][e] = (f16)src[e];
            }
            #pragma unroll
            for (int kt = 0; kt < 2; kt++) {
                const float* src = Wih + grow * I_ + kt * 32 + quad * 8;
                #pragma unroll
                for (int e = 0; e < 8; e++) wxA[g3][kt][e] = (f16)src[e];
            }
        }
        float b_r4[4], b_z4[4], b_ni4[4], b_nh4[4], vw4[4];
        #pragma unroll
        for (int r = 0; r < 4; r++) {
            const int ub = HS * j + wv * 16 + quad * 4 + r;
            b_r4[r]  = bih[ub] + bhh[ub];
            b_z4[r]  = bih[H_ + ub] + bhh[H_ + ub];
            b_ni4[r] = bih[2 * H_ + ub];
            b_nh4[r] = bhh[2 * H_ + ub];
            vw4[r]   = vw[ub];
        }
        float hprev[4] = {0.f, 0.f, 0.f, 0.f};
        unsigned int* myflag = gflags + (j * 2 + wv) * FLAG_STRIDE;
        const int sl = j * 2 + wv;
        const float bias0 = bias[0];

        __syncthreads();   // init: sh_h slot 0 zeroed

        #pragma unroll 1
        for (int t = 0; t < T_; t++) {
            // X_t fragments (wave-private, cached): B[k=quad*8+e][n=mrow] = X[t][b0+mrow][k]
            const float* xb = X + (size_t)t * (B_ * I_) + (size_t)(b0 + mrow) * I_ + quad * 8;
            const float4 xa0 = *(const float4*)xb;
            const float4 xa1 = *(const float4*)(xb + 4);
            const float4 xc0 = *(const float4*)(xb + 32);
            const float4 xc1 = *(const float4*)(xb + 36);

            // h_{t-1} B-fragments from LDS ping-pong + 48 h-MFMAs (hides X latency)
            const f16* hrow = &sh_h[t & 1][mrow][quad * 8];
            const f32x4 zero = {0.f, 0.f, 0.f, 0.f};
            f32x4 a_r = zero, a_z = zero, a_nh = zero;
            #pragma unroll
            for (int kt = 0; kt < 16; kt++) {
                f16x8 hb = *(const f16x8*)(hrow + kt * 32);
                a_r  = __builtin_amdgcn_mfma_f32_16x16x32_f16(wh[0][kt], hb, a_r,  0, 0, 0);
                a_z  = __builtin_amdgcn_mfma_f32_16x16x32_f16(wh[1][kt], hb, a_z,  0, 0, 0);
                a_nh = __builtin_amdgcn_mfma_f32_16x16x32_f16(wh[2][kt], hb, a_nh, 0, 0, 0);
            }
            f16x8 bx0 = {(f16)xa0.x,(f16)xa0.y,(f16)xa0.z,(f16)xa0.w,
                         (f16)xa1.x,(f16)xa1.y,(f16)xa1.z,(f16)xa1.w};
            f16x8 bx1 = {(f16)xc0.x,(f16)xc0.y,(f16)xc0.z,(f16)xc0.w,
                         (f16)xc1.x,(f16)xc1.y,(f16)xc1.z,(f16)xc1.w};
            f32x4 a_ni = __builtin_amdgcn_mfma_f32_16x16x32_f16(wxA[2][0], bx0, zero, 0, 0, 0);
            a_ni = __builtin_amdgcn_mfma_f32_16x16x32_f16(wxA[2][1], bx1, a_ni, 0, 0, 0);
            a_r  = __builtin_amdgcn_mfma_f32_16x16x32_f16(wxA[0][0], bx0, a_r,  0, 0, 0);
            a_r  = __builtin_amdgcn_mfma_f32_16x16x32_f16(wxA[0][1], bx1, a_r,  0, 0, 0);
            a_z  = __builtin_amdgcn_mfma_f32_16x16x32_f16(wxA[1][0], bx0, a_z,  0, 0, 0);
            a_z  = __builtin_amdgcn_mfma_f32_16x16x32_f16(wxA[1][1], bx1, a_z,  0, 0, 0);

            // gates in registers; one 8B write-through h-store per lane
            float hn[4];
            union { f16 h[4]; u32x2 v; } pk;
            #pragma unroll
            for (int r = 0; r < 4; r++) {
                float rg = sigmoid_f(a_r[r] + b_r4[r]);
                float zg = sigmoid_f(a_z[r] + b_z4[r]);
                float ng = tanh_f(a_ni[r] + b_ni4[r] + rg * (a_nh[r] + b_nh4[r]));
                hn[r] = (1.f - zg) * ng + zg * hprev[r];
                hprev[r] = hn[r];
                pk.h[r] = (f16)hn[r];
            }
            {
                f16* hp = hbuf + (size_t)(t & 1) * (B_ * H_)
                        + (size_t)(b0 + mrow) * H_ + HS * j + wv * 16 + quad * 4;
                asm volatile("global_store_dwordx2 %0, %1, off sc0 sc1"
                             :: "v"(hp), "v"(pk.v) : "memory");
            }
            // value head partial (overlaps store round trip)
            float s = hn[0] * vw4[0] + hn[1] * vw4[1] + hn[2] * vw4[2] + hn[3] * vw4[3];
            s += __shfl_xor(s, 16);
            s += __shfl_xor(s, 32);

            asm volatile("s_waitcnt vmcnt(0)" ::: "memory");  // h at MALL before flag
            if (lane == 0)
                __hip_atomic_store(myflag, (unsigned)(t + 1),
                                   __ATOMIC_RELAXED, __HIP_MEMORY_SCOPE_AGENT);
            if (quad == 0) {
                if (use_part) part[(size_t)sl * (T_ * B_) + (size_t)t * B_ + b0 + mrow] = s;
                else atomicAdd(&Vout[(size_t)t * B_ + b0 + mrow], s + (sl == 0 ? bias0 : 0.f));
            }
            __syncthreads();   // join with service: sh_h[(t+1)&1] = h_t is ready
        }
    } else {
        // ============== service wave: flag poll + h_t -> LDS prefetch ==============
        __syncthreads();   // init
        #pragma unroll 1
        for (int t = 0; t < T_; t++) {
            if (t + 1 < T_) {
                const unsigned target = (unsigned)(t + 1);
                for (;;) {   // one MALL round trip per iteration: 32 flags via ballot
                    unsigned v = target;
                    if (lane < 32)
                        v = __hip_atomic_load(gflags + lane * FLAG_STRIDE,
                                              __ATOMIC_RELAXED, __HIP_MEMORY_SCOPE_AGENT);
                    if (__ballot(v >= target) == ~0ull) break;
                    __builtin_amdgcn_s_sleep(1);
                }
                // h_t: 16 KB -> 16 x 16B per lane (lane = chunk, loop = row), one drain
                f16x8 hv[16];
                const f16* p0 = hbuf + (size_t)(t & 1) * (B_ * H_)
                              + (size_t)b0 * H_ + lane * 8;
                const f16* p1 = p0 + 4 * H_;
                const f16* p2 = p0 + 8 * H_;
                const f16* p3 = p0 + 12 * H_;
                asm volatile(
                    "global_load_dwordx4 %0, %16, off sc0 sc1\n\t"
                    "global_load_dwordx4 %1, %16, off offset:1024 sc0 sc1\n\t"
                    "global_load_dwordx4 %2, %16, off offset:2048 sc0 sc1\n\t"
                    "global_load_dwordx4 %3, %16, off offset:3072 sc0 sc1\n\t"
                    "global_load_dwordx4 %4, %17, off sc0 sc1\n\t"
                    "global_load_dwordx4 %5, %17, off offset:1024 sc0 sc1\n\t"
                    "global_load_dwordx4 %6, %17, off offset:2048 sc0 sc1\n\t"
                    "global_load_dwordx4 %7, %17, off offset:3072 sc0 sc1\n\t"
                    "global_load_dwordx4 %8, %18, off sc0 sc1\n\t"
                    "global_load_dwordx4 %9, %18, off offset:1024 sc0 sc1\n\t"
                    "global_load_dwordx4 %10, %18, off offset:2048 sc0 sc1\n\t"
                    "global_load_dwordx4 %11, %18, off offset:3072 sc0 sc1\n\t"
                    "global_load_dwordx4 %12, %19, off sc0 sc1\n\t"
                    "global_load_dwordx4 %13, %19, off offset:1024 sc0 sc1\n\t"
                    "global_load_dwordx4 %14, %19, off offset:2048 sc0 sc1\n\t"
                    "global_load_dwordx4 %15, %19, off offset:3072 sc0 sc1\n\t"
                    "s_waitcnt vmcnt(0)"
                    : "=&v"(hv[0]), "=&v"(hv[1]), "=&v"(hv[2]), "=&v"(hv[3]),
                      "=&v"(hv[4]), "=&v"(hv[5]), "=&v"(hv[6]), "=&v"(hv[7]),
                      "=&v"(hv[8]), "=&v"(hv[9]), "=&v"(hv[10]), "=&v"(hv[11]),
                      "=&v"(hv[12]), "=&v"(hv[13]), "=&v"(hv[14]), "=&v"(hv[15])
                    : "v"(p0), "v"(p1), "v"(p2), "v"(p3)
                    : "memory");
                char* dst = (char*)&sh_h[(t + 1) & 1][0][0] + (size_t)lane * 16;
                #pragma unroll
                for (int i = 0; i < 16; i++)     // row i, chunk `lane`: uniform bank windows
                    *(f16x8*)(dst + i * (HROW * 2)) = hv[i];
            }
            __syncthreads();
        }
    }
}

__global__ __launch_bounds__(256) void value_reduce(
    const float* __restrict__ part, const float* __restrict__ bias,
    float* __restrict__ Vout)
{
    const int i = blockIdx.x * 256 + threadIdx.x;   // i < T_*B_
    float s = bias[0];
    #pragma unroll
    for (int sl = 0; sl < NSL; sl++) s += part[(size_t)sl * (T_ * B_) + i];
    Vout[i] = s;
}

extern "C" void kernel_launch(void* const* d_in, const int* in_sizes, int n_in,
                              void* d_out, int out_size, void* d_ws, size_t ws_size,
                              hipStream_t stream) {
    const float* X    = (const float*)d_in[0];
    const float* Wih  = (const float*)d_in[1];
    const float* Whh  = (const float*)d_in[2];
    const float* bih  = (const float*)d_in[3];
    const float* bhh  = (const float*)d_in[4];
    const float* vw   = (const float*)d_in[5];
    const float* bias = (const float*)d_in[6];
    float* Vout = (float*)d_out;

    f16* hbuf = (f16*)d_ws;                                    // 512 KB, no init needed
    const size_t hbytes    = (size_t)2 * B_ * H_ * sizeof(f16);
    const size_t flagbytes = (size_t)NBG * 32 * FLAG_STRIDE * sizeof(unsigned);  // 32 KB
    unsigned int* flags = (unsigned int*)((char*)d_ws + hbytes);
    float* part = (float*)((char*)d_ws + hbytes + flagbytes);
    const size_t partbytes = (size_t)NSL * T_ * B_ * sizeof(float);              // 16.8 MB
    const int use_part = (ws_size >= hbytes + flagbytes + partbytes) ? 1 : 0;

    hipMemsetAsync(flags, 0, flagbytes, stream);   // flags at MALL: replay-safe reset
    if (!use_part)
        hipMemsetAsync(d_out, 0, (size_t)out_size * sizeof(float), stream);

    gru_persistent<<<256, BLOCK, 0, stream>>>(X, Wih, Whh, bih, bhh, vw, bias,
                                              Vout, hbuf, flags, part, use_part);
    if (use_part)
        value_reduce<<<(T_ * B_) / 256, 256, 0, stream>>>(part, bias, Vout);
}

// Round 7
// 1664.225 us; speedup vs baseline: 1.2599x; 1.2599x over previous
//
#include <hip/hip_runtime.h>
#include <hip/hip_fp16.h>

// Persistent fused GRU + value head, MI355X (gfx950).
// T=512,B=256,I=64,H=512. 256 blocks = 16 batch groups x 16 hidden slices.
// R7 = R4 loop structure (MFMA waves load h themselves; service wave stages X)
//    + R6 flag sync consumed directly by MFMA waves (ballot over 32 per-wave
//      flag words, ZERO atomics/RMWs) + operand swap (weights=A, 8B h-stores).
// All cross-block state at the MALL (sc0sc1 / agent ops) — replay-safe.

#define T_  512
#define B_  256
#define I_  64
#define H_  512
#define NBG 16
#define NHS 16
#define BT  16                  // batch rows per group
#define HS  32                  // hidden units per block
#define BLOCK 192
#define NSL 32                  // value-head slices (j,wv)
#define FLAG_STRIDE 32          // dwords: 128 B between flag words

typedef _Float16 f16;
typedef _Float16 f16x8 __attribute__((ext_vector_type(8)));
typedef float    f32x4 __attribute__((ext_vector_type(4)));
typedef unsigned int u32x2 __attribute__((ext_vector_type(2)));

__device__ __forceinline__ float sigmoid_f(float x) { return 1.f / (1.f + __expf(-x)); }
__device__ __forceinline__ float tanh_f(float x) {
    float e2 = __expf(2.f * x);
    return 1.f - 2.f / (e2 + 1.f);
}

__global__ __launch_bounds__(BLOCK, 1) void gru_persistent(
    const float* __restrict__ X, const float* __restrict__ Wih,
    const float* __restrict__ Whh, const float* __restrict__ bih,
    const float* __restrict__ bhh, const float* __restrict__ vw,
    const float* __restrict__ bias, float* __restrict__ Vout,
    f16* __restrict__ hbuf, unsigned int* __restrict__ flags,
    float* __restrict__ part, const int use_part)
{
    const int blk  = blockIdx.x;
    const int g    = (blk & 7) * 2 + (blk >> 7);   // group members share blk%8 (XCD heuristic)
    const int j    = (blk >> 3) & 15;
    const int b0   = g * BT;
    const int tid  = threadIdx.x;
    const int wv   = tid >> 6;
    const int lane = tid & 63;
    const int quad = lane >> 4;
    const int mrow = lane & 15;

    __shared__ __align__(16) f16 sh_x[2][BT][I_ + 8];   // X_t ping-pong (f16), padded
    unsigned int* gflags = flags + (size_t)g * (32 * FLAG_STRIDE);

    if (wv < 2) {
        // ============ MFMA waves: weights=A (units on M), h/x=B (batch on N) ============
        // A[m=lane&15 -> unit][k=quad*8+e]; D: row=quad*4+r -> unit, col=lane&15 -> batch
        f16x8 wh[3][16];
        f16x8 wxA[3][2];
        const int um = HS * j + wv * 16 + mrow;
        #pragma unroll
        for (int g3 = 0; g3 < 3; g3++) {
            const size_t grow = (size_t)(g3 * H_ + um);
            #pragma unroll
            for (int kt = 0; kt < 16; kt++) {
                const float* src = Whh + grow * H_ + kt * 32 + quad * 8;
                #pragma unroll
                for (int e = 0; e < 8; e++) wh[g3][kt][e] = (f16)src[e];
            }
            #pragma unroll
            for (int kt = 0; kt < 2; kt++) {
                const float* src = Wih + grow * I_ + kt * 32 + quad * 8;
                #pragma unroll
                for (int e = 0; e < 8; e++) wxA[g3][kt][e] = (f16)src[e];
            }
        }
        float b_r4[4], b_z4[4], b_ni4[4], b_nh4[4], vw4[4];
        #pragma unroll
        for (int r = 0; r < 4; r++) {
            const int ub = HS * j + wv * 16 + quad * 4 + r;
            b_r4[r]  = bih[ub] + bhh[ub];
            b_z4[r]  = bih[H_ + ub] + bhh[H_ + ub];
            b_ni4[r] = bih[2 * H_ + ub];
            b_nh4[r] = bhh[2 * H_ + ub];
            vw4[r]   = vw[ub];
        }
        float hprev[4] = {0.f, 0.f, 0.f, 0.f};   // fp32 anchor for z*h (and t=0 zeros)
        unsigned int* myflag = gflags + (j * 2 + wv) * FLAG_STRIDE;
        const int sl = j * 2 + wv;
        const float bias0 = bias[0];

        __syncthreads();   // init: service staged X_0 into slot 0

        #pragma unroll 1
        for (int t = 0; t < T_; t++) {
            // ---- 1. direct ballot poll: all 32 peer flags >= t, one RT/iteration ----
            if (t > 0) {
                const unsigned target = (unsigned)t;
                for (;;) {
                    unsigned v = target;
                    if (lane < 32)
                        v = __hip_atomic_load(gflags + lane * FLAG_STRIDE,
                                              __ATOMIC_RELAXED, __HIP_MEMORY_SCOPE_AGENT);
                    if (__ballot(v >= target) == ~0ull) break;
                }
            }

            // ---- 2. h_{t-1} B-fragments from the MALL: 16 x 16B, one drain ----
            f16x8 afr[16];
            const f16* abase = hbuf + (size_t)((t & 1) ^ 1) * (B_ * H_)
                             + (size_t)(b0 + mrow) * H_ + quad * 8;
            asm volatile(
                "global_load_dwordx4 %0, %16, off sc0 sc1\n\t"
                "global_load_dwordx4 %1, %16, off offset:64 sc0 sc1\n\t"
                "global_load_dwordx4 %2, %16, off offset:128 sc0 sc1\n\t"
                "global_load_dwordx4 %3, %16, off offset:192 sc0 sc1\n\t"
                "global_load_dwordx4 %4, %16, off offset:256 sc0 sc1\n\t"
                "global_load_dwordx4 %5, %16, off offset:320 sc0 sc1\n\t"
                "global_load_dwordx4 %6, %16, off offset:384 sc0 sc1\n\t"
                "global_load_dwordx4 %7, %16, off offset:448 sc0 sc1\n\t"
                "global_load_dwordx4 %8, %16, off offset:512 sc0 sc1\n\t"
                "global_load_dwordx4 %9, %16, off offset:576 sc0 sc1\n\t"
                "global_load_dwordx4 %10, %16, off offset:640 sc0 sc1\n\t"
                "global_load_dwordx4 %11, %16, off offset:704 sc0 sc1\n\t"
                "global_load_dwordx4 %12, %16, off offset:768 sc0 sc1\n\t"
                "global_load_dwordx4 %13, %16, off offset:832 sc0 sc1\n\t"
                "global_load_dwordx4 %14, %16, off offset:896 sc0 sc1\n\t"
                "global_load_dwordx4 %15, %16, off offset:960 sc0 sc1\n\t"
                "s_waitcnt vmcnt(0)"
                : "=&v"(afr[0]), "=&v"(afr[1]), "=&v"(afr[2]), "=&v"(afr[3]),
                  "=&v"(afr[4]), "=&v"(afr[5]), "=&v"(afr[6]), "=&v"(afr[7]),
                  "=&v"(afr[8]), "=&v"(afr[9]), "=&v"(afr[10]), "=&v"(afr[11]),
                  "=&v"(afr[12]), "=&v"(afr[13]), "=&v"(afr[14]), "=&v"(afr[15])
                : "v"(abase)
                : "memory");

            // ---- 3. MFMA: 48 h-MFMAs + 6 x-MFMAs ----
            f16x8 bx0 = *(const f16x8*)&sh_x[t & 1][mrow][quad * 8];
            f16x8 bx1 = *(const f16x8*)&sh_x[t & 1][mrow][32 + quad * 8];
            const f32x4 zero = {0.f, 0.f, 0.f, 0.f};
            f32x4 a_r  = __builtin_amdgcn_mfma_f32_16x16x32_f16(wxA[0][0], bx0, zero, 0, 0, 0);
            f32x4 a_z  = __builtin_amdgcn_mfma_f32_16x16x32_f16(wxA[1][0], bx0, zero, 0, 0, 0);
            f32x4 a_ni = __builtin_amdgcn_mfma_f32_16x16x32_f16(wxA[2][0], bx0, zero, 0, 0, 0);
            a_r  = __builtin_amdgcn_mfma_f32_16x16x32_f16(wxA[0][1], bx1, a_r,  0, 0, 0);
            a_z  = __builtin_amdgcn_mfma_f32_16x16x32_f16(wxA[1][1], bx1, a_z,  0, 0, 0);
            a_ni = __builtin_amdgcn_mfma_f32_16x16x32_f16(wxA[2][1], bx1, a_ni, 0, 0, 0);
            f32x4 a_nh = zero;
            #pragma unroll
            for (int kt = 0; kt < 16; kt++) {
                a_r  = __builtin_amdgcn_mfma_f32_16x16x32_f16(wh[0][kt], afr[kt], a_r,  0, 0, 0);
                a_z  = __builtin_amdgcn_mfma_f32_16x16x32_f16(wh[1][kt], afr[kt], a_z,  0, 0, 0);
                a_nh = __builtin_amdgcn_mfma_f32_16x16x32_f16(wh[2][kt], afr[kt], a_nh, 0, 0, 0);
            }

            // ---- 4. gates in registers; one 8B write-through h-store/lane ----
            float hn[4];
            union { f16 h[4]; u32x2 v; } pk;
            #pragma unroll
            for (int r = 0; r < 4; r++) {
                float rg = sigmoid_f(a_r[r] + b_r4[r]);
                float zg = sigmoid_f(a_z[r] + b_z4[r]);
                float ng = tanh_f(a_ni[r] + b_ni4[r] + rg * (a_nh[r] + b_nh4[r]));
                hn[r] = (1.f - zg) * ng + zg * hprev[r];
                hprev[r] = hn[r];
                pk.h[r] = (f16)hn[r];
            }
            {
                f16* hp = hbuf + (size_t)(t & 1) * (B_ * H_)
                        + (size_t)(b0 + mrow) * H_ + HS * j + wv * 16 + quad * 4;
                asm volatile("global_store_dwordx2 %0, %1, off sc0 sc1"
                             :: "v"(hp), "v"(pk.v) : "memory");
            }
            // value-head partial overlaps the store's flight time
            float s = hn[0] * vw4[0] + hn[1] * vw4[1] + hn[2] * vw4[2] + hn[3] * vw4[3];
            s += __shfl_xor(s, 16);
            s += __shfl_xor(s, 32);

            asm volatile("s_waitcnt vmcnt(0)" ::: "memory");   // h at MALL before flag
            if (lane == 0)
                __hip_atomic_store(myflag, (unsigned)(t + 1),
                                   __ATOMIC_RELAXED, __HIP_MEMORY_SCOPE_AGENT);
            if (quad == 0) {
                if (use_part) part[(size_t)sl * (T_ * B_) + (size_t)t * B_ + b0 + mrow] = s;
                else atomicAdd(&Vout[(size_t)t * B_ + b0 + mrow], s + (sl == 0 ? bias0 : 0.f));
            }
            __syncthreads();   // X ping-pong fence with service wave (off exchange path)
        }
    } else {
        // ============== service wave: X_{t+1} -> LDS ping-pong (off-path) ==============
        const int bb = lane >> 2, seg = (lane & 3) * 16;
        {   // stage X_0 -> slot 0
            const float* xs = X + (size_t)(b0 + bb) * I_ + seg;
            const float4 x0 = *(const float4*)(xs + 0),  x1 = *(const float4*)(xs + 4);
            const float4 x2 = *(const float4*)(xs + 8),  x3 = *(const float4*)(xs + 12);
            f16* dst = &sh_x[0][bb][seg];
            f16x8 p0 = {(f16)x0.x,(f16)x0.y,(f16)x0.z,(f16)x0.w,(f16)x1.x,(f16)x1.y,(f16)x1.z,(f16)x1.w};
            f16x8 p1 = {(f16)x2.x,(f16)x2.y,(f16)x2.z,(f16)x2.w,(f16)x3.x,(f16)x3.y,(f16)x3.z,(f16)x3.w};
            *(f16x8*)dst = p0; *(f16x8*)(dst + 8) = p1;
        }
        __syncthreads();   // init barrier
        #pragma unroll 1
        for (int t = 0; t < T_; t++) {
            if (t + 1 < T_) {
                const float* xs = X + (size_t)(t + 1) * (B_ * I_) + (size_t)(b0 + bb) * I_ + seg;
                const float4 x0 = *(const float4*)(xs + 0),  x1 = *(const float4*)(xs + 4);
                const float4 x2 = *(const float4*)(xs + 8),  x3 = *(const float4*)(xs + 12);
                f16* dst = &sh_x[(t + 1) & 1][bb][seg];
                f16x8 p0 = {(f16)x0.x,(f16)x0.y,(f16)x0.z,(f16)x0.w,(f16)x1.x,(f16)x1.y,(f16)x1.z,(f16)x1.w};
                f16x8 p1 = {(f16)x2.x,(f16)x2.y,(f16)x2.z,(f16)x2.w,(f16)x3.x,(f16)x3.y,(f16)x3.z,(f16)x3.w};
                *(f16x8*)dst = p0; *(f16x8*)(dst + 8) = p1;
            }
            __syncthreads();
        }
    }
}

__global__ __launch_bounds__(256) void value_reduce(
    const float* __restrict__ part, const float* __restrict__ bias,
    float* __restrict__ Vout)
{
    const int i = blockIdx.x * 256 + threadIdx.x;   // i < T_*B_
    float s = bias[0];
    #pragma unroll
    for (int sl = 0; sl < NSL; sl++) s += part[(size_t)sl * (T_ * B_) + i];
    Vout[i] = s;
}

extern "C" void kernel_launch(void* const* d_in, const int* in_sizes, int n_in,
                              void* d_out, int out_size, void* d_ws, size_t ws_size,
                              hipStream_t stream) {
    const float* X    = (const float*)d_in[0];
    const float* Wih  = (const float*)d_in[1];
    const float* Whh  = (const float*)d_in[2];
    const float* bih  = (const float*)d_in[3];
    const float* bhh  = (const float*)d_in[4];
    const float* vw   = (const float*)d_in[5];
    const float* bias = (const float*)d_in[6];
    float* Vout = (float*)d_out;

    f16* hbuf = (f16*)d_ws;
    const size_t hbytes    = (size_t)2 * B_ * H_ * sizeof(f16);                   // 512 KB
    const size_t flagbytes = (size_t)NBG * 32 * FLAG_STRIDE * sizeof(unsigned);   // 64 KB
    unsigned int* flags = (unsigned int*)((char*)d_ws + hbytes);
    float* part = (float*)((char*)d_ws + hbytes + flagbytes);
    const size_t partbytes = (size_t)NSL * T_ * B_ * sizeof(float);               // 16.8 MB
    const int use_part = (ws_size >= hbytes + flagbytes + partbytes) ? 1 : 0;

    hipMemsetAsync(d_ws, 0, hbytes + flagbytes, stream);   // hbuf zeros (t=0) + flags
    if (!use_part)
        hipMemsetAsync(d_out, 0, (size_t)out_size * sizeof(float), stream);

    gru_persistent<<<256, BLOCK, 0, stream>>>(X, Wih, Whh, bih, bhh, vw, bias,
                                              Vout, hbuf, flags, part, use_part);
    if (use_part)
        value_reduce<<<(T_ * B_) / 256, 256, 0, stream>>>(part, bias, Vout);
}